// Round 1
// baseline (245.387 us; speedup 1.0000x reference)
//
#include <hip/hip_runtime.h>
#include <hip/hip_bf16.h>

#define NNODES 16384
#define DNB 32

// ---------------------------------------------------------------------------
// Prep: qbias[c] = bq + btq + enc_t @ Wtq  (block 0)
//       Bk[c][h*64+k] = (c/16==h) ? Wtk[k][c] : 0   (blocks 1..256)
// ---------------------------------------------------------------------------
__global__ __launch_bounds__(256) void prep_kernel(
    const float* __restrict__ t, const float* __restrict__ bq,
    const float* __restrict__ btq, const float* __restrict__ Wtq,
    const float* __restrict__ w0, const float* __restrict__ b0,
    const float* __restrict__ Wt, const float* __restrict__ Bt,
    const float* __restrict__ Wtk,
    float* __restrict__ qbias, float* __restrict__ Bk)
{
    if (blockIdx.x == 0) {
        int c = threadIdx.x;
        if (c < 128) {
            float tv = t[0];
            float s = bq[c] + btq[c];
            float e0 = w0[0] * tv + b0[0];
            s += e0 * Wtq[c];                    // k = 0 row of Wtq
            for (int k = 1; k < 64; k++) {
                float e = __sinf(tv * Wt[k - 1] + Bt[k - 1]);
                s += e * Wtq[k * 128 + c];
            }
            qbias[c] = s;
        }
    } else {
        int i2 = (blockIdx.x - 1) * 256 + threadIdx.x;   // 0..65535
        int c = i2 >> 9;          // 0..127
        int j = i2 & 511;         // 0..511
        int h = j >> 6, k = j & 63;
        Bk[c * 512 + j] = ((c >> 4) == h) ? Wtk[k * 128 + c] : 0.0f;
    }
}

// ---------------------------------------------------------------------------
// Generic K=128 GEMM: C[r][c] = A[r][:128] @ W[:128][cb+c] (+bias)(+addsrc)(relu)
// BM=64, BN=64, 256 threads, 4x4 accumulators per thread.
// ---------------------------------------------------------------------------
__global__ __launch_bounds__(256) void gemm_k128(
    const float* __restrict__ A, const float* __restrict__ W, int ldw,
    const float* __restrict__ bias, const float* __restrict__ addsrc,
    float* __restrict__ C, int ldc, int relu)
{
    __shared__ float As[128][68];   // As[k][r]
    __shared__ float Ws[128][68];   // Ws[k][c]
    int t  = threadIdx.x;
    int rb = blockIdx.x * 64;
    int cb = blockIdx.y * 64;

    // stage A tile: 64 rows x 128 k (transposed into LDS)
    #pragma unroll
    for (int i = 0; i < 32; i++) {
        int idx = t + i * 256;
        int r = idx >> 7, k = idx & 127;
        As[k][r] = A[(size_t)(rb + r) * 128 + k];
    }
    // stage W tile: 128 k x 64 c
    #pragma unroll
    for (int i = 0; i < 32; i++) {
        int idx = t + i * 256;
        int k = idx >> 6, c = idx & 63;
        Ws[k][c] = W[(size_t)k * ldw + cb + c];
    }
    __syncthreads();

    int tr = t & 15, tc = t >> 4;
    int r0 = tr * 4, c0 = tc * 4;
    float acc[4][4] = {};
    #pragma unroll 8
    for (int k = 0; k < 128; k++) {
        float4 a = *(const float4*)&As[k][r0];
        float4 b = *(const float4*)&Ws[k][c0];
        acc[0][0] += a.x * b.x; acc[0][1] += a.x * b.y; acc[0][2] += a.x * b.z; acc[0][3] += a.x * b.w;
        acc[1][0] += a.y * b.x; acc[1][1] += a.y * b.y; acc[1][2] += a.y * b.z; acc[1][3] += a.y * b.w;
        acc[2][0] += a.z * b.x; acc[2][1] += a.z * b.y; acc[2][2] += a.z * b.z; acc[2][3] += a.z * b.w;
        acc[3][0] += a.w * b.x; acc[3][1] += a.w * b.y; acc[3][2] += a.w * b.z; acc[3][3] += a.w * b.w;
    }

    float4 bv = {0, 0, 0, 0};
    if (bias) bv = *(const float4*)&bias[cb + c0];
    #pragma unroll
    for (int i = 0; i < 4; i++) {
        size_t row = rb + r0 + i;
        float4 v;
        v.x = acc[i][0] + bv.x; v.y = acc[i][1] + bv.y;
        v.z = acc[i][2] + bv.z; v.w = acc[i][3] + bv.w;
        if (addsrc) {
            float4 ad = *(const float4*)&addsrc[row * ldc + cb + c0];
            v.x += ad.x; v.y += ad.y; v.z += ad.z; v.w += ad.w;
        }
        if (relu) {
            v.x = fmaxf(v.x, 0.f); v.y = fmaxf(v.y, 0.f);
            v.z = fmaxf(v.z, 0.f); v.w = fmaxf(v.w, 0.f);
        }
        *(float4*)&C[row * ldc + cb + c0] = v;
    }
}

// ---------------------------------------------------------------------------
// Attention: one wave per node. 4 waves / block, wave-private LDS (no barrier).
// ---------------------------------------------------------------------------
__global__ __launch_bounds__(256) void attn_kernel(
    const int*   __restrict__ neighbors, const float* __restrict__ times,
    const float* __restrict__ tptr,
    const float* __restrict__ Ktab, const float* __restrict__ Qtab,
    const float* __restrict__ Vtab, const float* __restrict__ G,
    const float* __restrict__ btk,  const float* __restrict__ Wtv,
    const float* __restrict__ btv,
    const float* __restrict__ w0,   const float* __restrict__ b0,
    const float* __restrict__ Wt,   const float* __restrict__ Bt,
    float* __restrict__ hbuf)
{
    __shared__ float enc[4][32][68];
    __shared__ float gbuf[4][512];
    __shared__ float qbuf[4][128];
    __shared__ float attnb[4][32][8];
    __shared__ float ewb[4][8][68];
    __shared__ int   nbb[4][32];
    __shared__ float cb_[4][8];

    int t = threadIdx.x;
    int wid = t >> 6, lane = t & 63;
    int n = blockIdx.x * 4 + wid;
    float t0 = tptr[0];

    // load q row and G row
    qbuf[wid][lane]      = Qtab[(size_t)n * 128 + lane];
    qbuf[wid][lane + 64] = Qtab[(size_t)n * 128 + 64 + lane];
    #pragma unroll
    for (int i = 0; i < 8; i++)
        gbuf[wid][lane + 64 * i] = G[(size_t)n * 512 + lane + 64 * i];

    int m = lane & 31, h2 = lane >> 5;
    if (lane < 32) nbb[wid][lane] = neighbors[n * 32 + lane];
    float tm = times[n * 32 + m];
    bool valid = (tm <= t0);

    // time encoding: lane(m,h2) writes k = 2i+h2
    float W0 = w0[0], B0 = b0[0];
    #pragma unroll 4
    for (int i = 0; i < 32; i++) {
        int k = 2 * i + h2;
        float v = (k == 0) ? (W0 * tm + B0)
                           : __sinf(tm * Wt[k - 1] + Bt[k - 1]);
        enc[wid][m][k] = v;
    }

    // c_h = qh . btk_h
    if (lane < 8) {
        float s = 0.f;
        for (int d = 0; d < 16; d++)
            s += qbuf[wid][lane * 16 + d] * btk[lane * 16 + d];
        cb_[wid][lane] = s;
    }

    // ---- scores: lane (m, h2) computes heads h = 4*h2 + hh ----
    float acc[4] = {0, 0, 0, 0};
    int nb = nbb[wid][m];
    const float4* Krow = (const float4*)(Ktab + (size_t)nb * 128);
    #pragma unroll
    for (int hh = 0; hh < 4; hh++) {
        int h = 4 * h2 + hh;
        float a = 0.f;
        #pragma unroll
        for (int d4 = 0; d4 < 4; d4++) {
            float4 q4 = *(const float4*)&qbuf[wid][h * 16 + 4 * d4];
            float4 k4 = Krow[h * 4 + d4];
            a += q4.x * k4.x + q4.y * k4.y + q4.z * k4.z + q4.w * k4.w;
        }
        acc[hh] = a;
    }
    #pragma unroll 4
    for (int k4 = 0; k4 < 16; k4++) {
        float4 e4 = *(const float4*)&enc[wid][m][4 * k4];
        #pragma unroll
        for (int hh = 0; hh < 4; hh++) {
            int h = 4 * h2 + hh;
            float4 g4 = *(const float4*)&gbuf[wid][h * 64 + 4 * k4];
            acc[hh] += e4.x * g4.x + e4.y * g4.y + e4.z * g4.z + e4.w * g4.w;
        }
    }

    unsigned long long bal = __ballot(valid);
    bool anyv = (bal != 0ull);

    // ---- softmax over m within each 32-lane half ----
    #pragma unroll
    for (int hh = 0; hh < 4; hh++) {
        float sc = valid ? 0.25f * (acc[hh] + cb_[wid][4 * h2 + hh]) : -1e9f;
        float mx = sc;
        for (int off = 16; off > 0; off >>= 1)
            mx = fmaxf(mx, __shfl_xor(mx, off));
        float p = __expf(sc - mx);
        float s = p;
        for (int off = 16; off > 0; off >>= 1)
            s += __shfl_xor(s, off);
        attnb[wid][m][4 * h2 + hh] = p / s;
    }

    // ---- e_w[h][k] = sum_m attn[m][h] * enc[m][k] ----
    {
        int eh = lane >> 3, qk = lane & 7;
        float4 ea = {0, 0, 0, 0}, eb = {0, 0, 0, 0};
        #pragma unroll 4
        for (int mm = 0; mm < 32; mm++) {
            float a = attnb[wid][mm][eh];
            float4 x1 = *(const float4*)&enc[wid][mm][4 * qk];
            float4 x2 = *(const float4*)&enc[wid][mm][4 * qk + 32];
            ea.x += a * x1.x; ea.y += a * x1.y; ea.z += a * x1.z; ea.w += a * x1.w;
            eb.x += a * x2.x; eb.y += a * x2.y; eb.z += a * x2.z; eb.w += a * x2.w;
        }
        *(float4*)&ewb[wid][eh][4 * qk]      = ea;
        *(float4*)&ewb[wid][eh][4 * qk + 32] = eb;
    }

    // ---- V aggregation + time-value term; lane handles cols lane, lane+64 ----
    float hv0 = 0.f, hv1 = 0.f;
    int ha = lane >> 4, hb = 4 + (lane >> 4);
    #pragma unroll 4
    for (int mm = 0; mm < 32; mm++) {
        int nbm = nbb[wid][mm];
        float a0 = attnb[wid][mm][ha];
        float a1 = attnb[wid][mm][hb];
        const float* Vr = Vtab + (size_t)nbm * 128;
        hv0 += a0 * Vr[lane];
        hv1 += a1 * Vr[lane + 64];
    }
    float ht0 = 0.f, ht1 = 0.f;
    #pragma unroll 8
    for (int k = 0; k < 64; k++) {
        ht0 += ewb[wid][ha][k] * Wtv[k * 128 + lane];
        ht1 += ewb[wid][hb][k] * Wtv[k * 128 + 64 + lane];
    }
    float o0 = anyv ? (hv0 + ht0 + btv[lane])      : 0.0f;
    float o1 = anyv ? (hv1 + ht1 + btv[lane + 64]) : 0.0f;
    hbuf[(size_t)n * 128 + lane]      = o0;
    hbuf[(size_t)n * 128 + 64 + lane] = o1;
}

// ---------------------------------------------------------------------------
extern "C" void kernel_launch(void* const* d_in, const int* in_sizes, int n_in,
                              void* d_out, int out_size, void* d_ws, size_t ws_size,
                              hipStream_t stream)
{
    const float* x        = (const float*)d_in[0];
    const int*   neighbors= (const int*)  d_in[1];
    const float* times    = (const float*)d_in[2];
    const float* t        = (const float*)d_in[3];
    const float* Wk  = (const float*)d_in[4];
    const float* bk  = (const float*)d_in[5];
    const float* Wq  = (const float*)d_in[6];
    const float* bq  = (const float*)d_in[7];
    const float* Wv  = (const float*)d_in[8];
    const float* bv  = (const float*)d_in[9];
    const float* w0  = (const float*)d_in[10];
    const float* b0  = (const float*)d_in[11];
    const float* Wt  = (const float*)d_in[12];
    const float* Bt  = (const float*)d_in[13];
    const float* Wtk = (const float*)d_in[14];
    const float* btk = (const float*)d_in[15];
    const float* Wtq = (const float*)d_in[16];
    const float* btq = (const float*)d_in[17];
    const float* Wtv = (const float*)d_in[18];
    const float* btv = (const float*)d_in[19];
    const float* W1  = (const float*)d_in[20];
    const float* b1  = (const float*)d_in[21];
    const float* W2  = (const float*)d_in[22];
    const float* b2  = (const float*)d_in[23];

    float* ws = (float*)d_ws;
    const size_t NF = (size_t)NNODES * 128;
    float* Ktab  = ws;
    float* Qtab  = Ktab + NF;
    float* Vtab  = Qtab + NF;
    float* Ptab  = Vtab + NF;
    float* hbuf  = Ptab + NF;
    float* Utab  = hbuf + NF;
    float* G     = Utab + NF;                    // N*512
    float* Bk    = G + (size_t)NNODES * 512;     // 128*512
    float* qbias = Bk + 128 * 512;               // 128

    prep_kernel<<<257, 256, 0, stream>>>(t, bq, btq, Wtq, w0, b0, Wt, Bt, Wtk,
                                         qbias, Bk);

    dim3 g2(NNODES / 64, 2);
    gemm_k128<<<g2, 256, 0, stream>>>(x, Wk, 128, bk,    nullptr, Ktab, 128, 0);
    gemm_k128<<<g2, 256, 0, stream>>>(x, Wq, 128, qbias, nullptr, Qtab, 128, 0);
    gemm_k128<<<g2, 256, 0, stream>>>(x, Wv, 128, bv,    nullptr, Vtab, 128, 0);
    gemm_k128<<<g2, 256, 0, stream>>>(x, W1, 128, b1,    nullptr, Ptab, 128, 0);

    dim3 g8(NNODES / 64, 8);
    gemm_k128<<<g8, 256, 0, stream>>>(Qtab, Bk, 512, nullptr, nullptr, G, 512, 0);

    attn_kernel<<<NNODES / 4, 256, 0, stream>>>(neighbors, times, t,
                                                Ktab, Qtab, Vtab, G,
                                                btk, Wtv, btv, w0, b0, Wt, Bt,
                                                hbuf);

    gemm_k128<<<g2, 256, 0, stream>>>(hbuf, W1 + 128 * 128, 128, nullptr, Ptab,
                                      Utab, 128, 1);
    gemm_k128<<<g2, 256, 0, stream>>>(Utab, W2, 128, b2, nullptr,
                                      (float*)d_out, 128, 0);
}

// Round 2
// 175.112 us; speedup vs baseline: 1.4013x; 1.4013x over previous
//
#include <hip/hip_runtime.h>
#include <hip/hip_bf16.h>

#define NNODES 16384

typedef unsigned short u16;
typedef unsigned int   u32;

__device__ __forceinline__ float bfl(u32 u) { return __uint_as_float(u << 16); }
__device__ __forceinline__ float bfh(u32 u) { return __uint_as_float(u & 0xffff0000u); }
__device__ __forceinline__ u16 f2b(float f) {
    u32 u = __float_as_uint(f);
    return (u16)((u + 0x7fffu + ((u >> 16) & 1u)) >> 16);
}

// ---------------------------------------------------------------------------
// qbias[c] = bq[c] + btq[c] + enc(t) @ Wtq[:,c]
// ---------------------------------------------------------------------------
__global__ void prep_kernel(
    const float* __restrict__ t, const float* __restrict__ bq,
    const float* __restrict__ btq, const float* __restrict__ Wtq,
    const float* __restrict__ w0, const float* __restrict__ b0,
    const float* __restrict__ Wt, const float* __restrict__ Bt,
    float* __restrict__ qbias)
{
    int c = threadIdx.x;
    if (c < 128) {
        float tv = t[0];
        float s = bq[c] + btq[c];
        float e0 = w0[0] * tv + b0[0];
        s += e0 * Wtq[c];
        for (int k = 1; k < 64; k++) {
            float e = __sinf(tv * Wt[k - 1] + Bt[k - 1]);
            s += e * Wtq[k * 128 + c];
        }
        qbias[c] = s;
    }
}

// ---------------------------------------------------------------------------
// G[n][h*64+k] = sum_{d<16} Qtab[n][h*16+d] * Wtk[k][h*16+d]   (bf16 out)
// thread = (n, h); 512 blocks x 256 threads
// ---------------------------------------------------------------------------
__global__ __launch_bounds__(256) void gcalc_kernel(
    const float* __restrict__ Qtab, const float* __restrict__ Wtk,
    u16* __restrict__ Gb)
{
    int t = blockIdx.x * 256 + threadIdx.x;
    int n = t >> 3, h = t & 7;
    float q[16];
    const float4* qp = (const float4*)(Qtab + (size_t)n * 128 + h * 16);
    #pragma unroll
    for (int i = 0; i < 4; i++) {
        float4 v = qp[i];
        q[4 * i] = v.x; q[4 * i + 1] = v.y; q[4 * i + 2] = v.z; q[4 * i + 3] = v.w;
    }
    u32 out[16];
    #pragma unroll
    for (int k4 = 0; k4 < 16; k4++) {
        float s[4];
        #pragma unroll
        for (int j = 0; j < 4; j++) {
            const float* wp = Wtk + (size_t)(4 * k4 + j) * 128 + h * 16;
            float a = 0.f;
            #pragma unroll
            for (int d = 0; d < 16; d++) a += q[d] * wp[d];
            s[j] = a;
        }
        out[2 * k4]     = (u32)f2b(s[0]) | ((u32)f2b(s[1]) << 16);
        out[2 * k4 + 1] = (u32)f2b(s[2]) | ((u32)f2b(s[3]) << 16);
    }
    int4* dst = (int4*)(Gb + (size_t)n * 512 + h * 64);
    const int4* src = (const int4*)out;
    #pragma unroll
    for (int i = 0; i < 4; i++) dst[i] = src[i];
}

// ---------------------------------------------------------------------------
// K=128 GEMM: C = A[:, :128] @ W (+bias) (+addsrc) (relu); f32 or bf16 out.
// ---------------------------------------------------------------------------
__global__ __launch_bounds__(256) void gemm_k128(
    const float* __restrict__ A, const float* __restrict__ W, int ldw,
    const float* __restrict__ bias, const float* __restrict__ addsrc,
    float* __restrict__ C, u16* __restrict__ Cb, int ldc, int relu)
{
    __shared__ float As[128][68];
    __shared__ float Ws[128][68];
    int t  = threadIdx.x;
    int rb = blockIdx.x * 64;
    int cb = blockIdx.y * 64;

    #pragma unroll
    for (int i = 0; i < 32; i++) {
        int idx = t + i * 256;
        int r = idx >> 7, k = idx & 127;
        As[k][r] = A[(size_t)(rb + r) * 128 + k];
    }
    #pragma unroll
    for (int i = 0; i < 32; i++) {
        int idx = t + i * 256;
        int k = idx >> 6, c = idx & 63;
        Ws[k][c] = W[(size_t)k * ldw + cb + c];
    }
    __syncthreads();

    int tr = t & 15, tc = t >> 4;
    int r0 = tr * 4, c0 = tc * 4;
    float acc[4][4] = {};
    #pragma unroll 8
    for (int k = 0; k < 128; k++) {
        float4 a = *(const float4*)&As[k][r0];
        float4 b = *(const float4*)&Ws[k][c0];
        acc[0][0] += a.x * b.x; acc[0][1] += a.x * b.y; acc[0][2] += a.x * b.z; acc[0][3] += a.x * b.w;
        acc[1][0] += a.y * b.x; acc[1][1] += a.y * b.y; acc[1][2] += a.y * b.z; acc[1][3] += a.y * b.w;
        acc[2][0] += a.z * b.x; acc[2][1] += a.z * b.y; acc[2][2] += a.z * b.z; acc[2][3] += a.z * b.w;
        acc[3][0] += a.w * b.x; acc[3][1] += a.w * b.y; acc[3][2] += a.w * b.z; acc[3][3] += a.w * b.w;
    }

    float4 bv = {0, 0, 0, 0};
    if (bias) bv = *(const float4*)&bias[cb + c0];
    #pragma unroll
    for (int i = 0; i < 4; i++) {
        size_t row = rb + r0 + i;
        float4 v;
        v.x = acc[i][0] + bv.x; v.y = acc[i][1] + bv.y;
        v.z = acc[i][2] + bv.z; v.w = acc[i][3] + bv.w;
        if (addsrc) {
            float4 ad = *(const float4*)&addsrc[row * 128 + cb + c0];
            v.x += ad.x; v.y += ad.y; v.z += ad.z; v.w += ad.w;
        }
        if (relu) {
            v.x = fmaxf(v.x, 0.f); v.y = fmaxf(v.y, 0.f);
            v.z = fmaxf(v.z, 0.f); v.w = fmaxf(v.w, 0.f);
        }
        if (Cb) {
            ushort4 s;
            s.x = f2b(v.x); s.y = f2b(v.y); s.z = f2b(v.z); s.w = f2b(v.w);
            *(ushort4*)&Cb[row * ldc + cb + c0] = s;
        } else {
            *(float4*)&C[row * ldc + cb + c0] = v;
        }
    }
}

// ---------------------------------------------------------------------------
// Attention: one wave per node, 4 waves/block, wave-private LDS (no barriers).
// K/V/G tables in bf16; ~37 KB LDS -> 4 blocks/CU (16 waves, was 8).
// ---------------------------------------------------------------------------
__global__ __launch_bounds__(256) void attn_kernel(
    const int*   __restrict__ neighbors, const float* __restrict__ times,
    const float* __restrict__ tptr,
    const u16* __restrict__ Kb, const float* __restrict__ Qtab,
    const u16* __restrict__ Vb, const u16* __restrict__ Gb,
    const float* __restrict__ btk,  const float* __restrict__ Wtv,
    const float* __restrict__ btv,
    const float* __restrict__ w0,   const float* __restrict__ b0,
    const float* __restrict__ Wt,   const float* __restrict__ Bt,
    float* __restrict__ hbuf)
{
    __shared__ u16   enc[4][32][68];
    __shared__ u16   gb[4][512];
    __shared__ float qbuf[4][128];
    __shared__ float attnb[4][32][9];
    __shared__ float ewb[4][8][68];
    __shared__ int   nbb[4][32];
    __shared__ float cb_[4][8];

    int t = threadIdx.x;
    int wid = t >> 6, lane = t & 63;
    int n = blockIdx.x * 4 + wid;
    float t0 = tptr[0];

    qbuf[wid][lane]      = Qtab[(size_t)n * 128 + lane];
    qbuf[wid][lane + 64] = Qtab[(size_t)n * 128 + 64 + lane];
    *(int4*)&gb[wid][8 * lane] = *(const int4*)(Gb + (size_t)n * 512 + 8 * lane);

    int m = lane & 31, h2 = lane >> 5;
    if (lane < 32) nbb[wid][lane] = neighbors[n * 32 + lane];
    float tm = times[n * 32 + m];
    bool valid = (tm <= t0);

    // time encoding: lane (m,h2) computes k in [32*h2, 32*h2+32), packed pairs
    float W0 = w0[0], B0 = b0[0];
    int kbase = 32 * h2;
    #pragma unroll 4
    for (int i = 0; i < 16; i++) {
        int k0 = kbase + 2 * i;
        float v0 = (k0 == 0) ? (W0 * tm + B0) : __sinf(tm * Wt[k0 - 1] + Bt[k0 - 1]);
        float v1 = __sinf(tm * Wt[k0] + Bt[k0]);
        *(u32*)&enc[wid][m][k0] = (u32)f2b(v0) | ((u32)f2b(v1) << 16);
    }

    if (lane < 8) {
        float s = 0.f;
        for (int d = 0; d < 16; d++)
            s += qbuf[wid][lane * 16 + d] * btk[lane * 16 + d];
        cb_[wid][lane] = s;
    }

    // ---- scores: lane (m,h2) computes heads h = 4*h2+hh ----
    float acc[4] = {0, 0, 0, 0};
    int nb = nbb[wid][m];
    const int4* Kr = (const int4*)(Kb + (size_t)nb * 128 + h2 * 64);
    #pragma unroll
    for (int j = 0; j < 8; j++) {
        int4 kk = Kr[j];
        int hh = j >> 1, d0 = (j & 1) * 8;
        const float* qp = &qbuf[wid][(4 * h2 + hh) * 16 + d0];
        acc[hh] += bfl(kk.x) * qp[0] + bfh(kk.x) * qp[1]
                 + bfl(kk.y) * qp[2] + bfh(kk.y) * qp[3]
                 + bfl(kk.z) * qp[4] + bfh(kk.z) * qp[5]
                 + bfl(kk.w) * qp[6] + bfh(kk.w) * qp[7];
    }
    #pragma unroll 4
    for (int c = 0; c < 16; c++) {
        int2 ev = *(const int2*)&enc[wid][m][4 * c];
        float e0 = bfl(ev.x), e1 = bfh(ev.x), e2 = bfl(ev.y), e3 = bfh(ev.y);
        #pragma unroll
        for (int hh = 0; hh < 4; hh++) {
            int h = 4 * h2 + hh;
            int2 gv = *(const int2*)&gb[wid][h * 64 + 4 * c];
            acc[hh] += e0 * bfl(gv.x) + e1 * bfh(gv.x)
                     + e2 * bfl(gv.y) + e3 * bfh(gv.y);
        }
    }

    unsigned long long bal = __ballot(valid);
    bool anyv = (bal != 0ull);

    // ---- softmax over m within each 32-lane half ----
    #pragma unroll
    for (int hh = 0; hh < 4; hh++) {
        float sc = valid ? 0.25f * (acc[hh] + cb_[wid][4 * h2 + hh]) : -1e9f;
        float mx = sc;
        for (int off = 16; off > 0; off >>= 1)
            mx = fmaxf(mx, __shfl_xor(mx, off));
        float p = __expf(sc - mx);
        float s = p;
        for (int off = 16; off > 0; off >>= 1)
            s += __shfl_xor(s, off);
        attnb[wid][m][4 * h2 + hh] = p / s;
    }

    // ---- ewb[h][k] = sum_m attn[m][h] * enc[m][k] ----
    {
        int eh = lane >> 3, qk = lane & 7;
        float4 ea = {0, 0, 0, 0}, eb4 = {0, 0, 0, 0};
        #pragma unroll 4
        for (int mm = 0; mm < 32; mm++) {
            float a = attnb[wid][mm][eh];
            int2 x1 = *(const int2*)&enc[wid][mm][4 * qk];
            int2 x2 = *(const int2*)&enc[wid][mm][4 * qk + 32];
            ea.x  += a * bfl(x1.x); ea.y  += a * bfh(x1.x);
            ea.z  += a * bfl(x1.y); ea.w  += a * bfh(x1.y);
            eb4.x += a * bfl(x2.x); eb4.y += a * bfh(x2.x);
            eb4.z += a * bfl(x2.y); eb4.w += a * bfh(x2.y);
        }
        *(float4*)&ewb[wid][eh][4 * qk]      = ea;
        *(float4*)&ewb[wid][eh][4 * qk + 32] = eb4;
    }

    // ---- V aggregation; lane owns cols (2*lane, 2*lane+1), head = lane>>3 ----
    int myh = lane >> 3;
    float av0 = 0.f, av1 = 0.f;
    #pragma unroll 8
    for (int mm = 0; mm < 32; mm++) {
        int nbm = nbb[wid][mm];
        float a = attnb[wid][mm][myh];
        u32 vv = *(const u32*)(Vb + (size_t)nbm * 128 + 2 * lane);
        av0 += a * bfl(vv);
        av1 += a * bfh(vv);
    }
    float ht0 = 0.f, ht1 = 0.f;
    #pragma unroll 8
    for (int k = 0; k < 64; k++) {
        float ew = ewb[wid][myh][k];
        float2 wv = *(const float2*)&Wtv[k * 128 + 2 * lane];
        ht0 += ew * wv.x;
        ht1 += ew * wv.y;
    }
    float2 bt2 = *(const float2*)&btv[2 * lane];
    float2 o;
    o.x = anyv ? (av0 + ht0 + bt2.x) : 0.0f;
    o.y = anyv ? (av1 + ht1 + bt2.y) : 0.0f;
    *(float2*)&hbuf[(size_t)n * 128 + 2 * lane] = o;
}

// ---------------------------------------------------------------------------
extern "C" void kernel_launch(void* const* d_in, const int* in_sizes, int n_in,
                              void* d_out, int out_size, void* d_ws, size_t ws_size,
                              hipStream_t stream)
{
    const float* x        = (const float*)d_in[0];
    const int*   neighbors= (const int*)  d_in[1];
    const float* times    = (const float*)d_in[2];
    const float* t        = (const float*)d_in[3];
    const float* Wk  = (const float*)d_in[4];
    const float* bk  = (const float*)d_in[5];
    const float* Wq  = (const float*)d_in[6];
    const float* bq  = (const float*)d_in[7];
    const float* Wv  = (const float*)d_in[8];
    const float* bv  = (const float*)d_in[9];
    const float* w0  = (const float*)d_in[10];
    const float* b0  = (const float*)d_in[11];
    const float* Wt  = (const float*)d_in[12];
    const float* Bt  = (const float*)d_in[13];
    const float* Wtk = (const float*)d_in[14];
    const float* btk = (const float*)d_in[15];
    const float* Wtq = (const float*)d_in[16];
    const float* btq = (const float*)d_in[17];
    const float* Wtv = (const float*)d_in[18];
    const float* btv = (const float*)d_in[19];
    const float* W1  = (const float*)d_in[20];
    const float* b1  = (const float*)d_in[21];
    const float* W2  = (const float*)d_in[22];
    const float* b2  = (const float*)d_in[23];

    float* ws = (float*)d_ws;
    const size_t NF = (size_t)NNODES * 128;
    float* Qtab  = ws;                                   // NF f32
    float* Ptab  = Qtab + NF;                            // NF f32
    float* hbuf  = Ptab + NF;                            // NF f32
    float* Utab  = hbuf + NF;                            // NF f32
    u16*   Kb    = (u16*)(Utab + NF);                    // NF bf16
    u16*   Vb    = Kb + NF;                              // NF bf16
    u16*   Gb    = Vb + NF;                              // N*512 bf16
    float* qbias = (float*)(Gb + (size_t)NNODES * 512);  // 128 f32

    prep_kernel<<<1, 128, 0, stream>>>(t, bq, btq, Wtq, w0, b0, Wt, Bt, qbias);

    dim3 g2(NNODES / 64, 2);
    gemm_k128<<<g2, 256, 0, stream>>>(x, Wk, 128, bk,    nullptr, nullptr, Kb,  128, 0);
    gemm_k128<<<g2, 256, 0, stream>>>(x, Wq, 128, qbias, nullptr, Qtab, nullptr, 128, 0);
    gemm_k128<<<g2, 256, 0, stream>>>(x, Wv, 128, bv,    nullptr, nullptr, Vb,  128, 0);
    gemm_k128<<<g2, 256, 0, stream>>>(x, W1, 128, b1,    nullptr, Ptab, nullptr, 128, 0);

    gcalc_kernel<<<NNODES * 8 / 256, 256, 0, stream>>>(Qtab, Wtk, Gb);

    attn_kernel<<<NNODES / 4, 256, 0, stream>>>(neighbors, times, t,
                                                Kb, Qtab, Vb, Gb,
                                                btk, Wtv, btv, w0, b0, Wt, Bt,
                                                hbuf);

    gemm_k128<<<g2, 256, 0, stream>>>(hbuf, W1 + 128 * 128, 128, nullptr, Ptab,
                                      Utab, nullptr, 128, 1);
    gemm_k128<<<g2, 256, 0, stream>>>(Utab, W2, 128, b2, nullptr,
                                      (float*)d_out, nullptr, 128, 0);
}

// Round 3
// 161.925 us; speedup vs baseline: 1.5154x; 1.0814x over previous
//
#include <hip/hip_runtime.h>
#include <hip/hip_bf16.h>

#define NNODES 16384

typedef unsigned short u16;
typedef unsigned int   u32;

__device__ __forceinline__ float bfl(u32 u) { return __uint_as_float(u << 16); }
__device__ __forceinline__ float bfh(u32 u) { return __uint_as_float(u & 0xffff0000u); }
__device__ __forceinline__ u16 f2b(float f) {
    u32 u = __float_as_uint(f);
    return (u16)((u + 0x7fffu + ((u >> 16) & 1u)) >> 16);
}

// ---------------------------------------------------------------------------
// qbias[c] = bq[c] + btq[c] + enc(t) @ Wtq[:,c]
// ---------------------------------------------------------------------------
__global__ void prep_kernel(
    const float* __restrict__ t, const float* __restrict__ bq,
    const float* __restrict__ btq, const float* __restrict__ Wtq,
    const float* __restrict__ w0, const float* __restrict__ b0,
    const float* __restrict__ Wt, const float* __restrict__ Bt,
    float* __restrict__ qbias)
{
    int c = threadIdx.x;
    if (c < 128) {
        float tv = t[0];
        float s = bq[c] + btq[c];
        float e0 = w0[0] * tv + b0[0];
        s += e0 * Wtq[c];
        for (int k = 1; k < 64; k++) {
            float e = __sinf(tv * Wt[k - 1] + Bt[k - 1]);
            s += e * Wtq[k * 128 + c];
        }
        qbias[c] = s;
    }
}

// ---------------------------------------------------------------------------
// G[n][h*64+k] = sum_{d<16} Qtab[n][h*16+d] * Wtk[k][h*16+d]   (bf16 out)
// ---------------------------------------------------------------------------
__global__ __launch_bounds__(256) void gcalc_kernel(
    const float* __restrict__ Qtab, const float* __restrict__ Wtk,
    u16* __restrict__ Gb)
{
    int t = blockIdx.x * 256 + threadIdx.x;
    int n = t >> 3, h = t & 7;
    float q[16];
    const float4* qp = (const float4*)(Qtab + (size_t)n * 128 + h * 16);
    #pragma unroll
    for (int i = 0; i < 4; i++) {
        float4 v = qp[i];
        q[4 * i] = v.x; q[4 * i + 1] = v.y; q[4 * i + 2] = v.z; q[4 * i + 3] = v.w;
    }
    u32 out[16];
    #pragma unroll
    for (int k4 = 0; k4 < 16; k4++) {
        float s[4];
        #pragma unroll
        for (int j = 0; j < 4; j++) {
            const float* wp = Wtk + (size_t)(4 * k4 + j) * 128 + h * 16;
            float a = 0.f;
            #pragma unroll
            for (int d = 0; d < 16; d++) a += q[d] * wp[d];
            s[j] = a;
        }
        out[2 * k4]     = (u32)f2b(s[0]) | ((u32)f2b(s[1]) << 16);
        out[2 * k4 + 1] = (u32)f2b(s[2]) | ((u32)f2b(s[3]) << 16);
    }
    int4* dst = (int4*)(Gb + (size_t)n * 512 + h * 64);
    const int4* src = (const int4*)out;
    #pragma unroll
    for (int i = 0; i < 4; i++) dst[i] = src[i];
}

// ---------------------------------------------------------------------------
// Fused 4-matrix K=128 GEMM over x: sel=blockIdx.y picks (W, bias, dst, half).
//   mat 0: Kb (bf16)   mat 1: Qtab (f32)   mat 2: Vb (bf16)   mat 3: Ptab (f32)
// ---------------------------------------------------------------------------
__global__ __launch_bounds__(256) void gemm4(
    const float* __restrict__ x,
    const float* __restrict__ Wk, const float* __restrict__ Wq,
    const float* __restrict__ Wv, const float* __restrict__ W1,
    const float* __restrict__ bk, const float* __restrict__ qbias,
    const float* __restrict__ bv, const float* __restrict__ b1,
    u16* __restrict__ Kb, float* __restrict__ Qtab,
    u16* __restrict__ Vb, float* __restrict__ Ptab)
{
    __shared__ float As[128][68];
    __shared__ float Ws[128][68];
    int t  = threadIdx.x;
    int rb = blockIdx.x * 64;
    int sel = blockIdx.y;
    int mat = sel >> 1, cb = (sel & 1) * 64;
    const float* W    = (mat == 0) ? Wk : (mat == 1) ? Wq : (mat == 2) ? Wv : W1;
    const float* bias = (mat == 0) ? bk : (mat == 1) ? qbias : (mat == 2) ? bv : b1;

    #pragma unroll
    for (int i = 0; i < 32; i++) {
        int idx = t + i * 256;
        int r = idx >> 7, k = idx & 127;
        As[k][r] = x[(size_t)(rb + r) * 128 + k];
    }
    #pragma unroll
    for (int i = 0; i < 32; i++) {
        int idx = t + i * 256;
        int k = idx >> 6, c = idx & 63;
        Ws[k][c] = W[(size_t)k * 128 + cb + c];
    }
    __syncthreads();

    int tr = t & 15, tc = t >> 4;
    int r0 = tr * 4, c0 = tc * 4;
    float acc[4][4] = {};
    #pragma unroll 8
    for (int k = 0; k < 128; k++) {
        float4 a = *(const float4*)&As[k][r0];
        float4 b = *(const float4*)&Ws[k][c0];
        acc[0][0] += a.x * b.x; acc[0][1] += a.x * b.y; acc[0][2] += a.x * b.z; acc[0][3] += a.x * b.w;
        acc[1][0] += a.y * b.x; acc[1][1] += a.y * b.y; acc[1][2] += a.y * b.z; acc[1][3] += a.y * b.w;
        acc[2][0] += a.z * b.x; acc[2][1] += a.z * b.y; acc[2][2] += a.z * b.z; acc[2][3] += a.z * b.w;
        acc[3][0] += a.w * b.x; acc[3][1] += a.w * b.y; acc[3][2] += a.w * b.z; acc[3][3] += a.w * b.w;
    }

    float4 bv4 = *(const float4*)&bias[cb + c0];
    #pragma unroll
    for (int i = 0; i < 4; i++) {
        size_t row = rb + r0 + i;
        float4 v;
        v.x = acc[i][0] + bv4.x; v.y = acc[i][1] + bv4.y;
        v.z = acc[i][2] + bv4.z; v.w = acc[i][3] + bv4.w;
        if (mat == 0 || mat == 2) {
            ushort4 s;
            s.x = f2b(v.x); s.y = f2b(v.y); s.z = f2b(v.z); s.w = f2b(v.w);
            u16* dst = (mat == 0) ? Kb : Vb;
            *(ushort4*)&dst[row * 128 + cb + c0] = s;
        } else {
            float* dst = (mat == 1) ? Qtab : Ptab;
            *(float4*)&dst[row * 128 + cb + c0] = v;
        }
    }
}

// ---------------------------------------------------------------------------
// K=128 GEMM: C = A[:, :128] @ W (+bias) (+addsrc) (relu); f32 out.
// ---------------------------------------------------------------------------
__global__ __launch_bounds__(256) void gemm_k128(
    const float* __restrict__ A, const float* __restrict__ W,
    const float* __restrict__ bias, const float* __restrict__ addsrc,
    float* __restrict__ C, int relu)
{
    __shared__ float As[128][68];
    __shared__ float Ws[128][68];
    int t  = threadIdx.x;
    int rb = blockIdx.x * 64;
    int cb = blockIdx.y * 64;

    #pragma unroll
    for (int i = 0; i < 32; i++) {
        int idx = t + i * 256;
        int r = idx >> 7, k = idx & 127;
        As[k][r] = A[(size_t)(rb + r) * 128 + k];
    }
    #pragma unroll
    for (int i = 0; i < 32; i++) {
        int idx = t + i * 256;
        int k = idx >> 6, c = idx & 63;
        Ws[k][c] = W[(size_t)k * 128 + cb + c];
    }
    __syncthreads();

    int tr = t & 15, tc = t >> 4;
    int r0 = tr * 4, c0 = tc * 4;
    float acc[4][4] = {};
    #pragma unroll 8
    for (int k = 0; k < 128; k++) {
        float4 a = *(const float4*)&As[k][r0];
        float4 b = *(const float4*)&Ws[k][c0];
        acc[0][0] += a.x * b.x; acc[0][1] += a.x * b.y; acc[0][2] += a.x * b.z; acc[0][3] += a.x * b.w;
        acc[1][0] += a.y * b.x; acc[1][1] += a.y * b.y; acc[1][2] += a.y * b.z; acc[1][3] += a.y * b.w;
        acc[2][0] += a.z * b.x; acc[2][1] += a.z * b.y; acc[2][2] += a.z * b.z; acc[2][3] += a.z * b.w;
        acc[3][0] += a.w * b.x; acc[3][1] += a.w * b.y; acc[3][2] += a.w * b.z; acc[3][3] += a.w * b.w;
    }

    float4 bv = {0, 0, 0, 0};
    if (bias) bv = *(const float4*)&bias[cb + c0];
    #pragma unroll
    for (int i = 0; i < 4; i++) {
        size_t row = rb + r0 + i;
        float4 v;
        v.x = acc[i][0] + bv.x; v.y = acc[i][1] + bv.y;
        v.z = acc[i][2] + bv.z; v.w = acc[i][3] + bv.w;
        if (addsrc) {
            float4 ad = *(const float4*)&addsrc[row * 128 + cb + c0];
            v.x += ad.x; v.y += ad.y; v.z += ad.z; v.w += ad.w;
        }
        if (relu) {
            v.x = fmaxf(v.x, 0.f); v.y = fmaxf(v.y, 0.f);
            v.z = fmaxf(v.z, 0.f); v.w = fmaxf(v.w, 0.f);
        }
        *(float4*)&C[row * 128 + cb + c0] = v;
    }
}

// ---------------------------------------------------------------------------
// Attention: one wave per node, 4 waves/block, wave-private LDS (no barriers).
// LDS 40832 B -> 4 blocks/CU. G unpacked to f32 LDS once/wave; V rows
// preloaded into VGPRs right after neighbor indices to hide gather latency.
// ---------------------------------------------------------------------------
__global__ __launch_bounds__(256, 4) void attn_kernel(
    const int*   __restrict__ neighbors, const float* __restrict__ times,
    const float* __restrict__ tptr,
    const u16* __restrict__ Kb, const float* __restrict__ Qtab,
    const u16* __restrict__ Vb, const u16* __restrict__ Gb,
    const float* __restrict__ btk,  const float* __restrict__ Wtv,
    const float* __restrict__ btv,
    const float* __restrict__ w0,   const float* __restrict__ b0,
    const float* __restrict__ Wt,   const float* __restrict__ Bt,
    float* __restrict__ hbuf)
{
    __shared__ u16   enc[4][32][66];    // 16896 B
    __shared__ float gbf[4][8][68];     //  8704 B (f32 g, unpacked once)
    __shared__ float qbuf[4][128];      //  2048 B
    __shared__ float attnb[4][8][33];   //  4224 B ([h][m] layout)
    __shared__ float ewb[4][8][65];     //  8320 B
    __shared__ int   nbb[4][32];        //   512 B
    __shared__ float cb_[4][8];         //   128 B   (total 40832)

    int t = threadIdx.x;
    int wid = t >> 6, lane = t & 63;
    int n = blockIdx.x * 4 + wid;
    float t0 = tptr[0];

    qbuf[wid][lane]      = Qtab[(size_t)n * 128 + lane];
    qbuf[wid][lane + 64] = Qtab[(size_t)n * 128 + 64 + lane];

    int m = lane & 31, h2 = lane >> 5;
    if (lane < 32) nbb[wid][lane] = neighbors[n * 32 + lane];
    float tm = times[n * 32 + m];
    bool valid = (tm <= t0);

    // ---- V preload: issue all 32 gathers now, consume ~2000 cycles later ----
    u32 vpre[32];
    #pragma unroll
    for (int mm = 0; mm < 32; mm++) {
        int nbm = nbb[wid][mm];
        vpre[mm] = *(const u32*)(Vb + (size_t)nbm * 128 + 2 * lane);
    }

    // ---- G row: bf16 global -> f32 LDS (8 unpacks/lane, once) ----
    {
        int4 g4 = *(const int4*)(Gb + (size_t)n * 512 + 8 * lane);
        const u32* gw = (const u32*)&g4;
        #pragma unroll
        for (int i = 0; i < 4; i++) {
            int j = 8 * lane + 2 * i;
            gbf[wid][j >> 6][j & 63]       = bfl(gw[i]);
            gbf[wid][j >> 6][(j & 63) + 1] = bfh(gw[i]);
        }
    }

    // ---- time encoding: lane (m,h2) computes k in [32*h2, 32*h2+32) ----
    float W0 = w0[0], B0 = b0[0];
    int kbase = 32 * h2;
    #pragma unroll
    for (int i = 0; i < 16; i++) {
        int k0 = kbase + 2 * i;
        float v0 = (k0 == 0) ? (W0 * tm + B0) : __sinf(tm * Wt[k0 - 1] + Bt[k0 - 1]);
        float v1 = __sinf(tm * Wt[k0] + Bt[k0]);
        *(u32*)&enc[wid][m][k0] = (u32)f2b(v0) | ((u32)f2b(v1) << 16);
    }

    if (lane < 8) {
        float s = 0.f;
        #pragma unroll
        for (int d = 0; d < 16; d++)
            s += qbuf[wid][lane * 16 + d] * btk[lane * 16 + d];
        cb_[wid][lane] = s;
    }

    // ---- scores: lane (m,h2) computes heads h = 4*h2+hh ----
    float acc[4] = {0, 0, 0, 0};
    int nb = nbb[wid][m];
    const int4* Kr = (const int4*)(Kb + (size_t)nb * 128 + h2 * 64);
    #pragma unroll
    for (int j = 0; j < 8; j++) {
        int4 kk = Kr[j];
        int hh = j >> 1, d0 = (j & 1) * 8;
        const float* qp = &qbuf[wid][(4 * h2 + hh) * 16 + d0];
        acc[hh] += bfl(kk.x) * qp[0] + bfh(kk.x) * qp[1]
                 + bfl(kk.y) * qp[2] + bfh(kk.y) * qp[3]
                 + bfl(kk.z) * qp[4] + bfh(kk.z) * qp[5]
                 + bfl(kk.w) * qp[6] + bfh(kk.w) * qp[7];
    }
    #pragma unroll 4
    for (int c = 0; c < 16; c++) {
        u32 eA = *(const u32*)&enc[wid][m][4 * c];
        u32 eB = *(const u32*)&enc[wid][m][4 * c + 2];
        float e0 = bfl(eA), e1 = bfh(eA), e2 = bfl(eB), e3 = bfh(eB);
        #pragma unroll
        for (int hh = 0; hh < 4; hh++) {
            float4 g4 = *(const float4*)&gbf[wid][4 * h2 + hh][4 * c];
            acc[hh] += e0 * g4.x + e1 * g4.y + e2 * g4.z + e3 * g4.w;
        }
    }

    unsigned long long bal = __ballot(valid);
    bool anyv = (bal != 0ull);

    // ---- softmax over m within each 32-lane half ----
    #pragma unroll
    for (int hh = 0; hh < 4; hh++) {
        float sc = valid ? 0.25f * (acc[hh] + cb_[wid][4 * h2 + hh]) : -1e9f;
        float mx = sc;
        for (int off = 16; off > 0; off >>= 1)
            mx = fmaxf(mx, __shfl_xor(mx, off));
        float p = __expf(sc - mx);
        float s = p;
        for (int off = 16; off > 0; off >>= 1)
            s += __shfl_xor(s, off);
        attnb[wid][4 * h2 + hh][m] = p / s;
    }

    // ---- ewb[h][k] = sum_m attn[h][m] * enc[m][k] ----
    {
        int eh = lane >> 3, qk = lane & 7;
        float ea[4] = {0, 0, 0, 0}, eb[4] = {0, 0, 0, 0};
        #pragma unroll 4
        for (int mm = 0; mm < 32; mm++) {
            float a = attnb[wid][eh][mm];
            u32 xA = *(const u32*)&enc[wid][mm][4 * qk];
            u32 xB = *(const u32*)&enc[wid][mm][4 * qk + 2];
            u32 yA = *(const u32*)&enc[wid][mm][4 * qk + 32];
            u32 yB = *(const u32*)&enc[wid][mm][4 * qk + 34];
            ea[0] += a * bfl(xA); ea[1] += a * bfh(xA);
            ea[2] += a * bfl(xB); ea[3] += a * bfh(xB);
            eb[0] += a * bfl(yA); eb[1] += a * bfh(yA);
            eb[2] += a * bfl(yB); eb[3] += a * bfh(yB);
        }
        #pragma unroll
        for (int i = 0; i < 4; i++) {
            ewb[wid][eh][4 * qk + i]      = ea[i];
            ewb[wid][eh][4 * qk + 32 + i] = eb[i];
        }
    }

    // ---- V aggregation from preloaded registers; head = lane>>3 ----
    int myh = lane >> 3;
    float av0 = 0.f, av1 = 0.f;
    #pragma unroll
    for (int mm = 0; mm < 32; mm++) {
        float a = attnb[wid][myh][mm];
        av0 += a * bfl(vpre[mm]);
        av1 += a * bfh(vpre[mm]);
    }
    float ht0 = 0.f, ht1 = 0.f;
    #pragma unroll 8
    for (int k = 0; k < 64; k++) {
        float ew = ewb[wid][myh][k];
        float2 wv = *(const float2*)&Wtv[k * 128 + 2 * lane];
        ht0 += ew * wv.x;
        ht1 += ew * wv.y;
    }
    float2 bt2 = *(const float2*)&btv[2 * lane];
    float2 o;
    o.x = anyv ? (av0 + ht0 + bt2.x) : 0.0f;
    o.y = anyv ? (av1 + ht1 + bt2.y) : 0.0f;
    *(float2*)&hbuf[(size_t)n * 128 + 2 * lane] = o;
}

// ---------------------------------------------------------------------------
extern "C" void kernel_launch(void* const* d_in, const int* in_sizes, int n_in,
                              void* d_out, int out_size, void* d_ws, size_t ws_size,
                              hipStream_t stream)
{
    const float* x        = (const float*)d_in[0];
    const int*   neighbors= (const int*)  d_in[1];
    const float* times    = (const float*)d_in[2];
    const float* t        = (const float*)d_in[3];
    const float* Wk  = (const float*)d_in[4];
    const float* bk  = (const float*)d_in[5];
    const float* Wq  = (const float*)d_in[6];
    const float* bq  = (const float*)d_in[7];
    const float* Wv  = (const float*)d_in[8];
    const float* bv  = (const float*)d_in[9];
    const float* w0  = (const float*)d_in[10];
    const float* b0  = (const float*)d_in[11];
    const float* Wt  = (const float*)d_in[12];
    const float* Bt  = (const float*)d_in[13];
    const float* Wtk = (const float*)d_in[14];
    const float* btk = (const float*)d_in[15];
    const float* Wtq = (const float*)d_in[16];
    const float* btq = (const float*)d_in[17];
    const float* Wtv = (const float*)d_in[18];
    const float* btv = (const float*)d_in[19];
    const float* W1  = (const float*)d_in[20];
    const float* b1  = (const float*)d_in[21];
    const float* W2  = (const float*)d_in[22];
    const float* b2  = (const float*)d_in[23];

    float* ws = (float*)d_ws;
    const size_t NF = (size_t)NNODES * 128;
    float* Qtab  = ws;                                   // NF f32
    float* Ptab  = Qtab + NF;                            // NF f32
    float* hbuf  = Ptab + NF;                            // NF f32
    float* Utab  = hbuf + NF;                            // NF f32
    u16*   Kb    = (u16*)(Utab + NF);                    // NF bf16
    u16*   Vb    = Kb + NF;                              // NF bf16
    u16*   Gb    = Vb + NF;                              // N*512 bf16
    float* qbias = (float*)(Gb + (size_t)NNODES * 512);  // 128 f32

    prep_kernel<<<1, 128, 0, stream>>>(t, bq, btq, Wtq, w0, b0, Wt, Bt, qbias);

    gemm4<<<dim3(NNODES / 64, 8), 256, 0, stream>>>(
        x, Wk, Wq, Wv, W1, bk, qbias, bv, b1, Kb, Qtab, Vb, Ptab);

    gcalc_kernel<<<NNODES * 8 / 256, 256, 0, stream>>>(Qtab, Wtk, Gb);

    attn_kernel<<<NNODES / 4, 256, 0, stream>>>(neighbors, times, t,
                                                Kb, Qtab, Vb, Gb,
                                                btk, Wtv, btv, w0, b0, Wt, Bt,
                                                hbuf);

    dim3 g2(NNODES / 64, 2);
    gemm_k128<<<g2, 256, 0, stream>>>(hbuf, W1 + 128 * 128, nullptr, Ptab,
                                      Utab, 1);
    gemm_k128<<<g2, 256, 0, stream>>>(Utab, W2, b2, nullptr,
                                      (float*)d_out, 0);
}